// Round 15
// baseline (181.277 us; speedup 1.0000x reference)
//
#include <hip/hip_runtime.h>
#include <hip/hip_bf16.h>

// (B,N,D) = (4,4096,256) fp32 in/out.
//  wsplit: W fp32 -> (wh, wl) fp16 planes (proj VALU cut).
//  proj3:  fused q/k/v projection, 3-term fp16-split MFMA, fp16 out,
//          q pre-scaled by log2e. (engine verified R3-R14; W now pre-split)
//  transpose_v: v -> vT[d][n]   (verified)
//  frag_pass: rewrite kh and vT into MFMA-fragment-ordered global layouts
//          (kfrag/vfrag) so attn's K/V loads are contiguous 1KB coalesced
//          reads delivering byte-identical registers to R14's LDS path.
//  attn_flash10: R14 structure minus ALL K/V LDS machinery (R14 was
//          DS-pipe-bound: ~3.3K of 8.6K cyc/iter was kbuf reads + DMA-LDS
//          writes + Pex + shfl on one pipe). 512 blocks x 256 thr (4 waves,
//          244-VGPR budget), K/V streamed from kfrag/vfrag, LDS = dbuf Pex
//          (16KB) + mlbuf (2KB), ONE __syncthreads per 128-key iter,
//          R14 co-residency pairing.

#define SEQ   4096
#define DIM   256
#define LOG2E 1.4426950408889634f

typedef _Float16 f16;
typedef __attribute__((ext_vector_type(8)))  f16    f16x8;
typedef __attribute__((ext_vector_type(16))) float  f32x16;

// ---------------------------------------------------------------------------
// W fp32 [256][256] -> wh, wl fp16 [256][256]
// ---------------------------------------------------------------------------
__global__ __launch_bounds__(256) void wsplit(
    const float* __restrict__ W, f16* __restrict__ wh, f16* __restrict__ wl)
{
    const int i = blockIdx.x * 256 + threadIdx.x;   // grid 256 -> 65536 elems
    const float w = W[i];
    const f16 h = (f16)w;
    wh[i] = h;
    wl[i] = (f16)(w - (float)h);
}

// ---------------------------------------------------------------------------
// Fused projection (engine verified R3-R14; W pre-split to fp16 hi/lo).
// out = (X @ W^T + b) * scale, fp16.
// ---------------------------------------------------------------------------
__global__ __launch_bounds__(256) void proj3(
    const float* __restrict__ X,
    const f16* __restrict__ Whq, const f16* __restrict__ Wlq, const float* __restrict__ bq,
    const f16* __restrict__ Whk, const f16* __restrict__ Wlk, const float* __restrict__ bk,
    const f16* __restrict__ Whv, const f16* __restrict__ Wlv, const float* __restrict__ bv,
    f16* __restrict__ outq, f16* __restrict__ outk, f16* __restrict__ outv)
{
    const f16* Wh; const f16* Wl; const float* bias; f16* out; float scale;
    if (blockIdx.y == 0)      { Wh = Whq; Wl = Wlq; bias = bq; out = outq; scale = LOG2E; }
    else if (blockIdx.y == 1) { Wh = Whk; Wl = Wlk; bias = bk; out = outk; scale = 1.f; }
    else                      { Wh = Whv; Wl = Wlv; bias = bv; out = outv; scale = 1.f; }

    const int w = threadIdx.x >> 6, lane = threadIdx.x & 63;
    const int col = lane & 31, hi = lane >> 5;
    const int m0 = blockIdx.x * 64 + (w & 1) * 32;
    const int e0 = (w >> 1) * 128;

    f32x16 acc[4] = {};
    for (int s = 0; s < 16; ++s) {
        const float* xp = X + (size_t)(m0 + col) * DIM + s * 16 + 8 * hi;
        float xv[8];
        *(float4*)&xv[0] = *(const float4*)xp;
        *(float4*)&xv[4] = *(const float4*)(xp + 4);
        f16x8 xh, xl;
        #pragma unroll
        for (int i = 0; i < 8; ++i) {
            xh[i] = (f16)xv[i];
            xl[i] = (f16)(xv[i] - (float)xh[i]);
        }
        #pragma unroll
        for (int c = 0; c < 4; ++c) {
            const size_t wo = (size_t)(e0 + c * 32 + col) * DIM + s * 16 + 8 * hi;
            const f16x8 wh = *(const f16x8*)(Wh + wo);
            const f16x8 wl = *(const f16x8*)(Wl + wo);
            acc[c] = __builtin_amdgcn_mfma_f32_32x32x16_f16(xh, wh, acc[c], 0, 0, 0);
            acc[c] = __builtin_amdgcn_mfma_f32_32x32x16_f16(xl, wh, acc[c], 0, 0, 0);
            acc[c] = __builtin_amdgcn_mfma_f32_32x32x16_f16(xh, wl, acc[c], 0, 0, 0);
        }
    }
    #pragma unroll
    for (int c = 0; c < 4; ++c) {
        const int e = e0 + c * 32 + col;
        const float b = bias[e];
        #pragma unroll
        for (int r = 0; r < 16; ++r) {
            const int m = m0 + (r & 3) + 8 * (r >> 2) + 4 * hi;
            out[(size_t)m * DIM + e] = (f16)((acc[c][r] + b) * scale);
        }
    }
}

// ---------------------------------------------------------------------------
// v (fp16 [N][256] per batch) -> vT (fp16 [256][N] per batch)  (verified)
// ---------------------------------------------------------------------------
__global__ void transpose_v(const f16* __restrict__ v, f16* __restrict__ vT)
{
    __shared__ f16 tile[32][33];
    const size_t pp = (size_t)SEQ * DIM;
    const f16* vb = v + blockIdx.z * pp;
    f16* vTb = vT + blockIdx.z * pp;
    const int n0 = blockIdx.x * 32, e0 = blockIdx.y * 32;
    #pragma unroll
    for (int r = 0; r < 4; ++r)
        tile[threadIdx.y + 8 * r][threadIdx.x] =
            vb[(size_t)(n0 + threadIdx.y + 8 * r) * DIM + e0 + threadIdx.x];
    __syncthreads();
    #pragma unroll
    for (int r = 0; r < 4; ++r)
        vTb[(size_t)(e0 + threadIdx.y + 8 * r) * SEQ + n0 + threadIdx.x] =
            tile[threadIdx.x][threadIdx.y + 8 * r];
}

// ---------------------------------------------------------------------------
// frag_pass: rows -> MFMA B-fragment order.
// frag entry (blk, sl, l) = src[row0 + (l&31)][c0_f16 + 16*sl + 8*(l>>5) .. +8]
// mode 0 (K):  src = kh [4096][256], gx in [0,128): row0=32gx, c0=0,
//              dst blk = gx (1024 uint4 per blk: 16 slices).
// mode 1 (V):  src = vT [256][4096], gx in [0,256): cb=gx&7, t=gx>>3,
//              row0=32cb, c0=128t, dst blk = gx (512 uint4: 8 slices).
// Per-batch dst plane = 131072 uint4 (2 MB) for both.
// ---------------------------------------------------------------------------
__global__ __launch_bounds__(256) void frag_pass(
    const f16* __restrict__ src, uint4* __restrict__ dst, int mode)
{
    __shared__ uint4 lds[32][33];
    const int gx = blockIdx.x, b = blockIdx.y;
    const uint4* s4 = (const uint4*)(src + (size_t)b * SEQ * DIM);
    const int tau = threadIdx.x;

    if (mode == 0) {
        uint4* d4 = dst + (size_t)b * 131072 + (size_t)gx * 1024;
        const int row0 = 32 * gx;
        #pragma unroll
        for (int i = 0; i < 4; ++i) {            // load 32 rows x 32 uint4
            const int e = tau + 256 * i;
            lds[e >> 5][e & 31] = s4[(size_t)(row0 + (e >> 5)) * 32 + (e & 31)];
        }
        __syncthreads();
        #pragma unroll
        for (int i = 0; i < 4; ++i) {            // write 16 slices x 64 lanes
            const int e = tau + 256 * i;
            const int sl = e >> 6, l = e & 63;
            d4[e] = lds[l & 31][sl * 2 + (l >> 5)];
        }
    } else {
        uint4* d4 = dst + (size_t)b * 131072 + (size_t)gx * 512;
        const int row0 = 32 * (gx & 7);
        const int c0 = (gx >> 3) * 16;
        #pragma unroll
        for (int i = 0; i < 2; ++i) {            // load 32 rows x 16 uint4
            const int e = tau + 256 * i;
            lds[e >> 4][e & 15] = s4[(size_t)(row0 + (e >> 4)) * 512 + c0 + (e & 15)];
        }
        __syncthreads();
        #pragma unroll
        for (int i = 0; i < 2; ++i) {            // write 8 slices x 64 lanes
            const int e = tau + 256 * i;
            const int sl = e >> 6, l = e & 63;
            d4[e] = lds[l & 31][sl * 2 + (l >> 5)];
        }
    }
}

// ---------------------------------------------------------------------------
// attn_flash10: 32 q-rows/block, 4 waves, 128-key iters, K/V from fragment-
// ordered global, LDS only for Pex (dbuf) + mlbuf, one barrier per iter.
// ---------------------------------------------------------------------------
__global__ __launch_bounds__(256, 1) void attn_flash10(
    const f16* __restrict__ qh, const uint4* __restrict__ kfrag,
    const uint4* __restrict__ vfrag, float* __restrict__ out, int nb)
{
    __shared__ uint4 Pex[2][512];        // dbuf A-frags, 16 KB
    __shared__ float mlbuf[2][2][4][32]; // [buf][m|l][kq][q], 2 KB

    int qt, b;
    if (nb == 4) {
        const int lin = blockIdx.x;       // 512 blocks = 2/CU
        const int x = lin & 7;            // XCD
        b = x >> 1;                       // 2 XCDs per batch
        const int k = lin >> 3;           // slot k and k+32 share a CU
        const int f = (k < 32) ? k : (95 - k);   // f + f' = 63
        qt = 2 * f + (x & 1);             // [0,128)
    } else { qt = blockIdx.x; b = 0; }    // grid 128

    const size_t pp = (size_t)SEQ * DIM;
    const f16* qhb = qh + b * pp;
    const uint4* kfb = kfrag + (size_t)b * 131072;
    const uint4* vfb = vfrag + (size_t)b * 131072;
    float* outb = out + b * pp;

    const int wid = threadIdx.x >> 6, lane = threadIdx.x & 63;
    const int col = lane & 31, hi = lane >> 5;
    const int kq = wid;                   // 32-key quarter / 64-col quarter
    const int q0 = qt * 32;
    const int nt = (qt + 4) >> 2;         // 128-key tiles

    // Q fragments resident (single fp16, 64 VGPRs)
    f16x8 qhf[16];
    #pragma unroll
    for (int sl = 0; sl < 16; ++sl)
        qhf[sl] = *(const f16x8*)(qhb + (size_t)(q0 + col) * DIM + sl * 16 + 8 * hi);

    float m_run = -1e28f, l_run = 0.f;
    f32x16 oacc[2] = {};                  // cols 64*kq + {col, 32+col}

    for (int t = 0; t < nt; ++t) {
        const int key0 = t << 7;
        const int pb = t & 1;

        // ---- QK^T: own 32-key quarter, K frags from global (coalesced) ----
        const uint4* kp = kfb + (size_t)(4 * t + kq) * 1024 + lane;
        f32x16 s1 = {}, s2 = {};
        #pragma unroll
        for (int sl = 0; sl < 16; ++sl) {
            const f16x8 kf = __builtin_bit_cast(f16x8, kp[sl * 64]);
            if (sl & 1) s2 = __builtin_amdgcn_mfma_f32_32x32x16_f16(kf, qhf[sl], s2, 0, 0, 0);
            else        s1 = __builtin_amdgcn_mfma_f32_32x32x16_f16(kf, qhf[sl], s1, 0, 0, 0);
        }

        // ---- V prefetch A-half (slices 0..3, own 64-col quarter) ----
        const uint4* vp = vfb + (size_t)(8 * t + 2 * kq) * 512 + lane;
        f16x8 vfA[2][4];
        #pragma unroll
        for (int cg = 0; cg < 2; ++cg)
            #pragma unroll
            for (int s = 0; s < 4; ++s)
                vfA[cg][s] = __builtin_bit_cast(f16x8, vp[cg * 512 + s * 64]);

        // ---- mask + wave-local softmax (verified R10-R14 verbatim) ----
        float sv[16];
        float pmax = -1e30f, tsum = 0.f;
        #pragma unroll
        for (int r = 0; r < 16; ++r) {
            const int kg = key0 + 32 * kq + (r & 3) + 8 * (r >> 2) + 4 * hi;
            const float x = (kg <= q0 + col) ? (s1[r] + s2[r]) : -1e30f;
            sv[r] = x;
            pmax = fmaxf(pmax, x);
        }
        pmax = fmaxf(pmax, __shfl_xor(pmax, 32));
        pmax = fmaxf(pmax, -1e28f);       // fully-masked quarter -> p = 0
        {
            float p[16];
            #pragma unroll
            for (int r = 0; r < 16; ++r) {
                p[r] = exp2f(sv[r] - pmax);
                tsum += p[r];
            }
            tsum += __shfl_xor(tsum, 32);
            // A-frag build (verified cvt_pk + shfl_xor(32))
            uint32_t Wd[8], Od[8];
            #pragma unroll
            for (int jj = 0; jj < 8; ++jj)
                Wd[jj] = __builtin_bit_cast(uint32_t,
                    __builtin_amdgcn_cvt_pkrtz(p[2 * jj], p[2 * jj + 1]));
            #pragma unroll
            for (int jj = 0; jj < 8; ++jj)
                Od[jj] = (uint32_t)__shfl_xor((int)Wd[jj], 32);
            uint4 A0, A1;
            if (hi == 0) {
                A0.x = Wd[0]; A0.y = Wd[1]; A0.z = Od[0]; A0.w = Od[1];
                A1.x = Wd[4]; A1.y = Wd[5]; A1.z = Od[4]; A1.w = Od[5];
            } else {
                A0.x = Od[2]; A0.y = Od[3]; A0.z = Wd[2]; A0.w = Wd[3];
                A1.x = Od[6]; A1.y = Od[7]; A1.z = Wd[6]; A1.w = Wd[7];
            }
            Pex[pb][((2 * kq + 0) * 2 + hi) * 32 + col] = A0;  // keys [32kq,+16)
            Pex[pb][((2 * kq + 1) * 2 + hi) * 32 + col] = A1;  // keys [32kq+16,+16)
        }
        if (lane < 32) {
            mlbuf[pb][0][kq][col] = pmax;
            mlbuf[pb][1][kq][col] = tsum;
        }
        __syncthreads();                  // the ONLY barrier per iter

        // ---- V prefetch B-half (slices 4..7) ----
        f16x8 vfB[2][4];
        #pragma unroll
        for (int cg = 0; cg < 2; ++cg)
            #pragma unroll
            for (int s = 0; s < 4; ++s)
                vfB[cg][s] = __builtin_bit_cast(f16x8, vp[cg * 512 + (s + 4) * 64]);

        // ---- 4-way m/l merge (verified), defer-max rescale ----
        const float mw0 = mlbuf[pb][0][0][col], mw1 = mlbuf[pb][0][1][col];
        const float mw2 = mlbuf[pb][0][2][col], mw3 = mlbuf[pb][0][3][col];
        const float tw0 = mlbuf[pb][1][0][col], tw1 = mlbuf[pb][1][1][col];
        const float tw2 = mlbuf[pb][1][2][col], tw3 = mlbuf[pb][1][3][col];
        const float mt = fmaxf(fmaxf(mw0, mw1), fmaxf(mw2, mw3));
        float scale = 1.f;
        if (__any(mt > m_run + 11.5415603f)) {   // 8-nat window (log2)
            const float m_new = fmaxf(m_run, mt);
            scale = exp2f(m_run - m_new);
            m_run = m_new;
            #pragma unroll
            for (int r = 0; r < 16; ++r) {
                const int qr = (r & 3) + 8 * (r >> 2) + 4 * hi;
                const float scr = __shfl(scale, qr | (lane & 32));
                oacc[0][r] *= scr; oacc[1][r] *= scr;
            }
        }
        const float c0 = exp2f(mw0 - m_run), c1 = exp2f(mw1 - m_run);
        const float c2 = exp2f(mw2 - m_run), c3 = exp2f(mw3 - m_run);
        l_run = l_run * scale + tw0 * c0 + tw1 * c1 + tw2 * c2 + tw3 * c3;
        const f16 ch[4] = {(f16)c0, (f16)c1, (f16)c2, (f16)c3};

        // ---- PV: 8 slices x own 64-col quarter (V in regs) ----
        #pragma unroll
        for (int s4 = 0; s4 < 4; ++s4) {
            f16x8 af = __builtin_bit_cast(f16x8, Pex[pb][(s4 * 2 + hi) * 32 + col]);
            af = af * ch[s4 >> 1];
            oacc[0] = __builtin_amdgcn_mfma_f32_32x32x16_f16(af, vfA[0][s4], oacc[0], 0, 0, 0);
            oacc[1] = __builtin_amdgcn_mfma_f32_32x32x16_f16(af, vfA[1][s4], oacc[1], 0, 0, 0);
        }
        #pragma unroll
        for (int s4 = 0; s4 < 4; ++s4) {
            f16x8 af = __builtin_bit_cast(f16x8, Pex[pb][((s4 + 4) * 2 + hi) * 32 + col]);
            af = af * ch[2 + (s4 >> 1)];
            oacc[0] = __builtin_amdgcn_mfma_f32_32x32x16_f16(af, vfB[0][s4], oacc[0], 0, 0, 0);
            oacc[1] = __builtin_amdgcn_mfma_f32_32x32x16_f16(af, vfB[1][s4], oacc[1], 0, 0, 0);
        }
        // no iter-end barrier needed: next iter writes Pex[pb^1]/mlbuf[pb^1],
        // disjoint from any laggard's Pex[pb] reads; barrier(t+1) orders t+2.
    }

    // ---- epilogue: divide by l, store fp32 ----
    const float linv = 1.f / l_run;
    #pragma unroll
    for (int r = 0; r < 16; ++r) {
        const int qr = (r & 3) + 8 * (r >> 2) + 4 * hi;
        const float lr = __shfl(linv, qr | (lane & 32));
        const int n = q0 + qr;
        outb[(size_t)n * DIM + 64 * kq + col]      = oacc[0][r] * lr;
        outb[(size_t)n * DIM + 64 * kq + 32 + col] = oacc[1][r] * lr;
    }
}

// ---------------------------------------------------------------------------
extern "C" void kernel_launch(void* const* d_in, const int* in_sizes, int n_in,
                              void* d_out, int out_size, void* d_ws, size_t ws_size,
                              hipStream_t stream) {
    const float* x  = (const float*)d_in[0];
    const float* Wq = (const float*)d_in[1];
    const float* bq = (const float*)d_in[2];
    const float* Wk = (const float*)d_in[3];
    const float* bk = (const float*)d_in[4];
    const float* Wv = (const float*)d_in[5];
    const float* bv = (const float*)d_in[6];
    float* out = (float*)d_out;

    const size_t PP = (size_t)SEQ * DIM;            // 1M elems per batch plane
    const size_t FULL = 4 * PP;                     // 4M elems (8 MB fp16)
    const size_t WSZ = (size_t)DIM * DIM;           // 64K elems per W plane

    if (ws_size >= FULL * 2 * 5) {                  // known-true threshold (R1+)
        // planes: P0=qh, P1=kh->vfrag, P2=vv->kfrag, P3=vT, then 6 W halves
        f16* qh = (f16*)d_ws;
        f16* P1 = qh + FULL;
        f16* P2 = P1 + FULL;
        f16* vT = P2 + FULL;
        f16* wsp = vT + FULL;                       // 6 x 64K fp16 = 768 KB
        f16* whq = wsp;          f16* wlq = whq + WSZ;
        f16* whk = wlq + WSZ;    f16* wlk = whk + WSZ;
        f16* whv = wlk + WSZ;    f16* wlv = whv + WSZ;

        wsplit<<<dim3(256), 256, 0, stream>>>(Wq, whq, wlq);
        wsplit<<<dim3(256), 256, 0, stream>>>(Wk, whk, wlk);
        wsplit<<<dim3(256), 256, 0, stream>>>(Wv, whv, wlv);
        proj3<<<dim3(256, 3), 256, 0, stream>>>(
            x, whq, wlq, bq, whk, wlk, bk, whv, wlv, bv, qh, P1 /*kh*/, P2 /*vv*/);
        transpose_v<<<dim3(128, 8, 4), dim3(32, 8), 0, stream>>>(P2 /*vv*/, vT);
        frag_pass<<<dim3(128, 4), 256, 0, stream>>>(P1 /*kh*/, (uint4*)P2, 0); // kfrag->P2
        frag_pass<<<dim3(256, 4), 256, 0, stream>>>(vT, (uint4*)P1, 1);        // vfrag->P1
        attn_flash10<<<dim3(512), 256, 0, stream>>>(
            qh, (const uint4*)P2, (const uint4*)P1, out, 4);
    } else {
        // per-batch fallback (~8.8 MB)
        f16* qh = (f16*)d_ws;
        f16* P1 = qh + PP;
        f16* P2 = P1 + PP;
        f16* vT = P2 + PP;
        f16* wsp = vT + PP;
        f16* whq = wsp;          f16* wlq = whq + WSZ;
        f16* whk = wlq + WSZ;    f16* wlk = whk + WSZ;
        f16* whv = wlk + WSZ;    f16* wlv = whv + WSZ;

        wsplit<<<dim3(256), 256, 0, stream>>>(Wq, whq, wlq);
        wsplit<<<dim3(256), 256, 0, stream>>>(Wk, whk, wlk);
        wsplit<<<dim3(256), 256, 0, stream>>>(Wv, whv, wlv);
        for (int b = 0; b < 4; ++b) {
            const float* xb = x + b * PP;
            proj3<<<dim3(64, 3), 256, 0, stream>>>(
                xb, whq, wlq, bq, whk, wlk, bk, whv, wlv, bv, qh, P1, P2);
            transpose_v<<<dim3(128, 8, 1), dim3(32, 8), 0, stream>>>(P2, vT);
            frag_pass<<<dim3(128, 1), 256, 0, stream>>>(P1, (uint4*)P2, 0);
            frag_pass<<<dim3(256, 1), 256, 0, stream>>>(vT, (uint4*)P1, 1);
            attn_flash10<<<dim3(128), 256, 0, stream>>>(
                qh, (const uint4*)P2, (const uint4*)P1, out + b * PP, 1);
        }
    }
}

// Round 16
// 172.370 us; speedup vs baseline: 1.0517x; 1.0517x over previous
//
#include <hip/hip_runtime.h>
#include <hip/hip_bf16.h>

// (B,N,D) = (4,4096,256) fp32 in/out.
//  wsplit:     W fp32 -> (wh, wl) fp16, one launch for all 3 W's.
//  proj3:      fused q/k/v projection (verified R3-R15), fp16 out,
//              q pre-scaled by log2e.
//  kfrag_make: kh -> MFMA-fragment-ordered kfrag (verified R15 frag_pass m0).
//  vfrag_make: v  -> vfrag DIRECTLY (fuses R15's transpose_v + frag_pass m1;
//              index algebra = composition of the two verified kernels).
//  attn_flash11: R15 attn + K(t+1) half-tile register prefetch issued
//              pre-barrier (hides L2 latency under softmax+barrier+PV).
//              512 blocks x 256 thr (244-VGPR budget), K/V from fragment
//              global, LDS = dbuf Pex + mlbuf only, 1 barrier/iter,
//              R14 co-residency pairing.

#define SEQ   4096
#define DIM   256
#define LOG2E 1.4426950408889634f

typedef _Float16 f16;
typedef __attribute__((ext_vector_type(8)))  f16    f16x8;
typedef __attribute__((ext_vector_type(16))) float  f32x16;

// ---------------------------------------------------------------------------
// W fp32 [256][256] -> wh, wl fp16. blockIdx.y selects which W.
// ---------------------------------------------------------------------------
__global__ __launch_bounds__(256) void wsplit(
    const float* __restrict__ Wq, const float* __restrict__ Wk,
    const float* __restrict__ Wv, f16* __restrict__ whq, f16* __restrict__ wlq,
    f16* __restrict__ whk, f16* __restrict__ wlk,
    f16* __restrict__ whv, f16* __restrict__ wlv)
{
    const float* W; f16* wh; f16* wl;
    if (blockIdx.y == 0)      { W = Wq; wh = whq; wl = wlq; }
    else if (blockIdx.y == 1) { W = Wk; wh = whk; wl = wlk; }
    else                      { W = Wv; wh = whv; wl = wlv; }
    const int i = blockIdx.x * 256 + threadIdx.x;   // grid.x 256 -> 65536
    const float w = W[i];
    const f16 h = (f16)w;
    wh[i] = h;
    wl[i] = (f16)(w - (float)h);
}

// ---------------------------------------------------------------------------
// Fused projection (verified). out = (X @ W^T + b) * scale, fp16.
// ---------------------------------------------------------------------------
__global__ __launch_bounds__(256) void proj3(
    const float* __restrict__ X,
    const f16* __restrict__ Whq, const f16* __restrict__ Wlq, const float* __restrict__ bq,
    const f16* __restrict__ Whk, const f16* __restrict__ Wlk, const float* __restrict__ bk,
    const f16* __restrict__ Whv, const f16* __restrict__ Wlv, const float* __restrict__ bv,
    f16* __restrict__ outq, f16* __restrict__ outk, f16* __restrict__ outv)
{
    const f16* Wh; const f16* Wl; const float* bias; f16* out; float scale;
    if (blockIdx.y == 0)      { Wh = Whq; Wl = Wlq; bias = bq; out = outq; scale = LOG2E; }
    else if (blockIdx.y == 1) { Wh = Whk; Wl = Wlk; bias = bk; out = outk; scale = 1.f; }
    else                      { Wh = Whv; Wl = Wlv; bias = bv; out = outv; scale = 1.f; }

    const int w = threadIdx.x >> 6, lane = threadIdx.x & 63;
    const int col = lane & 31, hi = lane >> 5;
    const int m0 = blockIdx.x * 64 + (w & 1) * 32;
    const int e0 = (w >> 1) * 128;

    f32x16 acc[4] = {};
    for (int s = 0; s < 16; ++s) {
        const float* xp = X + (size_t)(m0 + col) * DIM + s * 16 + 8 * hi;
        float xv[8];
        *(float4*)&xv[0] = *(const float4*)xp;
        *(float4*)&xv[4] = *(const float4*)(xp + 4);
        f16x8 xh, xl;
        #pragma unroll
        for (int i = 0; i < 8; ++i) {
            xh[i] = (f16)xv[i];
            xl[i] = (f16)(xv[i] - (float)xh[i]);
        }
        #pragma unroll
        for (int c = 0; c < 4; ++c) {
            const size_t wo = (size_t)(e0 + c * 32 + col) * DIM + s * 16 + 8 * hi;
            const f16x8 wh = *(const f16x8*)(Wh + wo);
            const f16x8 wl = *(const f16x8*)(Wl + wo);
            acc[c] = __builtin_amdgcn_mfma_f32_32x32x16_f16(xh, wh, acc[c], 0, 0, 0);
            acc[c] = __builtin_amdgcn_mfma_f32_32x32x16_f16(xl, wh, acc[c], 0, 0, 0);
            acc[c] = __builtin_amdgcn_mfma_f32_32x32x16_f16(xh, wl, acc[c], 0, 0, 0);
        }
    }
    #pragma unroll
    for (int c = 0; c < 4; ++c) {
        const int e = e0 + c * 32 + col;
        const float b = bias[e];
        #pragma unroll
        for (int r = 0; r < 16; ++r) {
            const int m = m0 + (r & 3) + 8 * (r >> 2) + 4 * hi;
            out[(size_t)m * DIM + e] = (f16)((acc[c][r] + b) * scale);
        }
    }
}

// ---------------------------------------------------------------------------
// kfrag_make (== verified R15 frag_pass mode 0): kh rows -> fragment order.
// kfrag[b][gx*1024 + sl*64 + l] = K[32gx + (l&31)][16sl + 8(l>>5) .. +8]
// ---------------------------------------------------------------------------
__global__ __launch_bounds__(256) void kfrag_make(
    const f16* __restrict__ kh, uint4* __restrict__ dst)
{
    __shared__ uint4 lds[32][33];
    const int gx = blockIdx.x, b = blockIdx.y;
    const uint4* s4 = (const uint4*)(kh + (size_t)b * SEQ * DIM);
    uint4* d4 = dst + (size_t)b * 131072 + (size_t)gx * 1024;
    const int tau = threadIdx.x;
    const int row0 = 32 * gx;
    #pragma unroll
    for (int i = 0; i < 4; ++i) {
        const int e = tau + 256 * i;
        lds[e >> 5][e & 31] = s4[(size_t)(row0 + (e >> 5)) * 32 + (e & 31)];
    }
    __syncthreads();
    #pragma unroll
    for (int i = 0; i < 4; ++i) {
        const int e = tau + 256 * i;
        const int sl = e >> 6, l = e & 63;
        d4[e] = lds[l & 31][sl * 2 + (l >> 5)];
    }
}

// ---------------------------------------------------------------------------
// vfrag_make: v [4096][256] -> vfrag directly (fuses transpose_v+frag_pass-V).
// Derivation (composition of the two verified kernels):
//   vfrag[b][gx*512 + sl*64 + l] = vT[32(gx&7) + (l&31)][128(gx>>3) + 16sl + 8(l>>5)..+8]
//                                = pack_i v[128(gx>>3) + 16sl + 8(l>>5) + i][32(gx&7) + (l&31)]
// Block (kb, db, b): kb = gx>>3 (128 keys), db = gx&7 (32 dims).
// ---------------------------------------------------------------------------
__global__ __launch_bounds__(256) void vfrag_make(
    const f16* __restrict__ v, uint4* __restrict__ dst)
{
    __shared__ f16 ldsT[32][136];        // [dim][key], rows 16B-aligned
    const int kb = blockIdx.x, db = blockIdx.y, b = blockIdx.z;
    const uint4* v4 = (const uint4*)(v + (size_t)b * SEQ * DIM);
    uint4* d4 = dst + (size_t)b * 131072 + (size_t)(8 * kb + db) * 512;
    const int tau = threadIdx.x;

    #pragma unroll
    for (int ii = 0; ii < 2; ++ii) {     // load 128 keys x 32 dims
        const int e = tau + 256 * ii;
        const int r = e >> 2, ch = e & 3;
        const uint4 u = v4[(size_t)(128 * kb + r) * 32 + db * 4 + ch];
        const f16* uf = (const f16*)&u;
        #pragma unroll
        for (int i = 0; i < 8; ++i) ldsT[8 * ch + i][r] = uf[i];
    }
    __syncthreads();
    #pragma unroll
    for (int ii = 0; ii < 2; ++ii) {     // write 8 slices x 64 lanes
        const int e = tau + 256 * ii;
        const int sl = e >> 6, l = e & 63;
        d4[e] = *(const uint4*)&ldsT[l & 31][16 * sl + 8 * (l >> 5)];
    }
}

// ---------------------------------------------------------------------------
// attn_flash11: R15 attn + pre-barrier K(t+1) half-prefetch.
// ---------------------------------------------------------------------------
__global__ __launch_bounds__(256, 1) void attn_flash11(
    const f16* __restrict__ qh, const uint4* __restrict__ kfrag,
    const uint4* __restrict__ vfrag, float* __restrict__ out, int nb)
{
    __shared__ uint4 Pex[2][512];        // dbuf A-frags, 16 KB
    __shared__ float mlbuf[2][2][4][32]; // [buf][m|l][kq][q], 2 KB

    int qt, b;
    if (nb == 4) {
        const int lin = blockIdx.x;       // 512 blocks = 2/CU
        const int x = lin & 7;            // XCD
        b = x >> 1;                       // 2 XCDs per batch
        const int k = lin >> 3;           // slot k and k+32 share a CU
        const int f = (k < 32) ? k : (95 - k);   // f + f' = 63
        qt = 2 * f + (x & 1);             // [0,128)
    } else { qt = blockIdx.x; b = 0; }    // grid 128

    const size_t pp = (size_t)SEQ * DIM;
    const f16* qhb = qh + b * pp;
    const uint4* kfb = kfrag + (size_t)b * 131072;
    const uint4* vfb = vfrag + (size_t)b * 131072;
    float* outb = out + b * pp;

    const int wid = threadIdx.x >> 6, lane = threadIdx.x & 63;
    const int col = lane & 31, hi = lane >> 5;
    const int kq = wid;                   // 32-key quarter / 64-col quarter
    const int q0 = qt * 32;
    const int nt = (qt + 4) >> 2;         // 128-key tiles

    // Q fragments resident (single fp16, 64 VGPRs)
    f16x8 qhf[16];
    #pragma unroll
    for (int sl = 0; sl < 16; ++sl)
        qhf[sl] = *(const f16x8*)(qhb + (size_t)(q0 + col) * DIM + sl * 16 + 8 * hi);

    // prologue: prefetch K slices 0..7 of tile 0
    uint4 kregA[8];
    {
        const uint4* kp0 = kfb + (size_t)kq * 1024 + lane;
        #pragma unroll
        for (int sl = 0; sl < 8; ++sl) kregA[sl] = kp0[sl * 64];
    }

    float m_run = -1e28f, l_run = 0.f;
    f32x16 oacc[2] = {};                  // cols 64*kq + {col, 32+col}

    for (int t = 0; t < nt; ++t) {
        const int key0 = t << 7;
        const int pb = t & 1;
        const uint4* kp = kfb + (size_t)(4 * t + kq) * 1024 + lane;

        // ---- QK^T: slices 0..7 from prefetched regs, 8..15 fresh ----
        f32x16 s1 = {}, s2 = {};
        #pragma unroll
        for (int sl = 0; sl < 8; ++sl) {
            const f16x8 kf = __builtin_bit_cast(f16x8, kregA[sl]);
            if (sl & 1) s2 = __builtin_amdgcn_mfma_f32_32x32x16_f16(kf, qhf[sl], s2, 0, 0, 0);
            else        s1 = __builtin_amdgcn_mfma_f32_32x32x16_f16(kf, qhf[sl], s1, 0, 0, 0);
        }
        #pragma unroll
        for (int sl = 8; sl < 16; ++sl) {
            const f16x8 kf = __builtin_bit_cast(f16x8, kp[sl * 64]);
            if (sl & 1) s2 = __builtin_amdgcn_mfma_f32_32x32x16_f16(kf, qhf[sl], s2, 0, 0, 0);
            else        s1 = __builtin_amdgcn_mfma_f32_32x32x16_f16(kf, qhf[sl], s1, 0, 0, 0);
        }

        // ---- V prefetch A-half (slices 0..3, own 64-col quarter) ----
        const uint4* vp = vfb + (size_t)(8 * t + 2 * kq) * 512 + lane;
        f16x8 vfA[2][4];
        #pragma unroll
        for (int cg = 0; cg < 2; ++cg)
            #pragma unroll
            for (int s = 0; s < 4; ++s)
                vfA[cg][s] = __builtin_bit_cast(f16x8, vp[cg * 512 + s * 64]);

        // ---- mask + wave-local softmax (verified R10-R15 verbatim) ----
        float sv[16];
        float pmax = -1e30f, tsum = 0.f;
        #pragma unroll
        for (int r = 0; r < 16; ++r) {
            const int kg = key0 + 32 * kq + (r & 3) + 8 * (r >> 2) + 4 * hi;
            const float x = (kg <= q0 + col) ? (s1[r] + s2[r]) : -1e30f;
            sv[r] = x;
            pmax = fmaxf(pmax, x);
        }
        pmax = fmaxf(pmax, __shfl_xor(pmax, 32));
        pmax = fmaxf(pmax, -1e28f);       // fully-masked quarter -> p = 0
        {
            float p[16];
            #pragma unroll
            for (int r = 0; r < 16; ++r) {
                p[r] = exp2f(sv[r] - pmax);
                tsum += p[r];
            }
            tsum += __shfl_xor(tsum, 32);
            // A-frag build (verified cvt_pk + shfl_xor(32))
            uint32_t Wd[8], Od[8];
            #pragma unroll
            for (int jj = 0; jj < 8; ++jj)
                Wd[jj] = __builtin_bit_cast(uint32_t,
                    __builtin_amdgcn_cvt_pkrtz(p[2 * jj], p[2 * jj + 1]));
            #pragma unroll
            for (int jj = 0; jj < 8; ++jj)
                Od[jj] = (uint32_t)__shfl_xor((int)Wd[jj], 32);
            uint4 A0, A1;
            if (hi == 0) {
                A0.x = Wd[0]; A0.y = Wd[1]; A0.z = Od[0]; A0.w = Od[1];
                A1.x = Wd[4]; A1.y = Wd[5]; A1.z = Od[4]; A1.w = Od[5];
            } else {
                A0.x = Od[2]; A0.y = Od[3]; A0.z = Wd[2]; A0.w = Wd[3];
                A1.x = Od[6]; A1.y = Od[7]; A1.z = Wd[6]; A1.w = Wd[7];
            }
            Pex[pb][((2 * kq + 0) * 2 + hi) * 32 + col] = A0;  // keys [32kq,+16)
            Pex[pb][((2 * kq + 1) * 2 + hi) * 32 + col] = A1;  // keys [32kq+16,+16)
        }
        if (lane < 32) {
            mlbuf[pb][0][kq][col] = pmax;
            mlbuf[pb][1][kq][col] = tsum;
        }

        // ---- prefetch K slices 0..7 of tile t+1 (pre-barrier: latency
        //      hidden under barrier + merge + PV) ----
        if (t + 1 < nt) {
            const uint4* kpn = kfb + (size_t)(4 * (t + 1) + kq) * 1024 + lane;
            #pragma unroll
            for (int sl = 0; sl < 8; ++sl) kregA[sl] = kpn[sl * 64];
        }
        __builtin_amdgcn_sched_barrier(0);   // pin prefetch issue point
        __syncthreads();                     // the ONLY barrier per iter

        // ---- V prefetch B-half (slices 4..7) ----
        f16x8 vfB[2][4];
        #pragma unroll
        for (int cg = 0; cg < 2; ++cg)
            #pragma unroll
            for (int s = 0; s < 4; ++s)
                vfB[cg][s] = __builtin_bit_cast(f16x8, vp[cg * 512 + (s + 4) * 64]);

        // ---- 4-way m/l merge (verified), defer-max rescale ----
        const float mw0 = mlbuf[pb][0][0][col], mw1 = mlbuf[pb][0][1][col];
        const float mw2 = mlbuf[pb][0][2][col], mw3 = mlbuf[pb][0][3][col];
        const float tw0 = mlbuf[pb][1][0][col], tw1 = mlbuf[pb][1][1][col];
        const float tw2 = mlbuf[pb][1][2][col], tw3 = mlbuf[pb][1][3][col];
        const float mt = fmaxf(fmaxf(mw0, mw1), fmaxf(mw2, mw3));
        float scale = 1.f;
        if (__any(mt > m_run + 11.5415603f)) {   // 8-nat window (log2)
            const float m_new = fmaxf(m_run, mt);
            scale = exp2f(m_run - m_new);
            m_run = m_new;
            #pragma unroll
            for (int r = 0; r < 16; ++r) {
                const int qr = (r & 3) + 8 * (r >> 2) + 4 * hi;
                const float scr = __shfl(scale, qr | (lane & 32));
                oacc[0][r] *= scr; oacc[1][r] *= scr;
            }
        }
        const float c0 = exp2f(mw0 - m_run), c1 = exp2f(mw1 - m_run);
        const float c2 = exp2f(mw2 - m_run), c3 = exp2f(mw3 - m_run);
        l_run = l_run * scale + tw0 * c0 + tw1 * c1 + tw2 * c2 + tw3 * c3;
        const f16 ch[4] = {(f16)c0, (f16)c1, (f16)c2, (f16)c3};

        // ---- PV: 8 slices x own 64-col quarter (V in regs) ----
        #pragma unroll
        for (int s4 = 0; s4 < 4; ++s4) {
            f16x8 af = __builtin_bit_cast(f16x8, Pex[pb][(s4 * 2 + hi) * 32 + col]);
            af = af * ch[s4 >> 1];
            oacc[0] = __builtin_amdgcn_mfma_f32_32x32x16_f16(af, vfA[0][s4], oacc[0], 0, 0, 0);
            oacc[1] = __builtin_amdgcn_mfma_f32_32x32x16_f16(af, vfA[1][s4], oacc[1], 0, 0, 0);
        }
        #pragma unroll
        for (int s4 = 0; s4 < 4; ++s4) {
            f16x8 af = __builtin_bit_cast(f16x8, Pex[pb][((s4 + 4) * 2 + hi) * 32 + col]);
            af = af * ch[2 + (s4 >> 1)];
            oacc[0] = __builtin_amdgcn_mfma_f32_32x32x16_f16(af, vfB[0][s4], oacc[0], 0, 0, 0);
            oacc[1] = __builtin_amdgcn_mfma_f32_32x32x16_f16(af, vfB[1][s4], oacc[1], 0, 0, 0);
        }
        // dbuf: next iter writes Pex[pb^1]/mlbuf[pb^1]; laggard's reads of
        // Pex[pb] are safe; barrier(t+1) orders reuse of Pex[pb] at t+2.
    }

    // ---- epilogue: divide by l, store fp32 ----
    const float linv = 1.f / l_run;
    #pragma unroll
    for (int r = 0; r < 16; ++r) {
        const int qr = (r & 3) + 8 * (r >> 2) + 4 * hi;
        const float lr = __shfl(linv, qr | (lane & 32));
        const int n = q0 + qr;
        outb[(size_t)n * DIM + 64 * kq + col]      = oacc[0][r] * lr;
        outb[(size_t)n * DIM + 64 * kq + 32 + col] = oacc[1][r] * lr;
    }
}

// ---------------------------------------------------------------------------
extern "C" void kernel_launch(void* const* d_in, const int* in_sizes, int n_in,
                              void* d_out, int out_size, void* d_ws, size_t ws_size,
                              hipStream_t stream) {
    const float* x  = (const float*)d_in[0];
    const float* Wq = (const float*)d_in[1];
    const float* bq = (const float*)d_in[2];
    const float* Wk = (const float*)d_in[3];
    const float* bk = (const float*)d_in[4];
    const float* Wv = (const float*)d_in[5];
    const float* bv = (const float*)d_in[6];
    float* out = (float*)d_out;

    const size_t PP = (size_t)SEQ * DIM;            // 1M elems per batch plane
    const size_t FULL = 4 * PP;                     // 4M elems (8 MB fp16)
    const size_t WSZ = (size_t)DIM * DIM;           // 64K elems per W plane

    if (ws_size >= FULL * 2 * 5) {                  // known-true threshold
        f16* qh  = (f16*)d_ws;
        f16* kh  = qh + FULL;
        f16* vv  = kh + FULL;
        f16* kfr = vv + FULL;                       // 8 MB (uint4 plane)
        f16* vfr = kfr + FULL;                      // 8 MB (uint4 plane)
        f16* wsp = vfr + FULL;                      // 6 x 64K fp16 = 768 KB
        f16* whq = wsp;          f16* wlq = whq + WSZ;
        f16* whk = wlq + WSZ;    f16* wlk = whk + WSZ;
        f16* whv = wlk + WSZ;    f16* wlv = whv + WSZ;

        wsplit<<<dim3(256, 3), 256, 0, stream>>>(Wq, Wk, Wv, whq, wlq, whk, wlk, whv, wlv);
        proj3<<<dim3(256, 3), 256, 0, stream>>>(
            x, whq, wlq, bq, whk, wlk, bk, whv, wlv, bv, qh, kh, vv);
        kfrag_make<<<dim3(128, 4), 256, 0, stream>>>(kh, (uint4*)kfr);
        vfrag_make<<<dim3(32, 8, 4), 256, 0, stream>>>(vv, (uint4*)vfr);
        attn_flash11<<<dim3(512), 256, 0, stream>>>(
            qh, (const uint4*)kfr, (const uint4*)vfr, out, 4);
    } else {
        // per-batch fallback (~11 MB)
        f16* qh  = (f16*)d_ws;
        f16* kh  = qh + PP;
        f16* vv  = kh + PP;
        f16* kfr = vv + PP;
        f16* vfr = kfr + PP;
        f16* wsp = vfr + PP;
        f16* whq = wsp;          f16* wlq = whq + WSZ;
        f16* whk = wlq + WSZ;    f16* wlk = whk + WSZ;
        f16* whv = wlk + WSZ;    f16* wlv = whv + WSZ;

        wsplit<<<dim3(256, 3), 256, 0, stream>>>(Wq, Wk, Wv, whq, wlq, whk, wlk, whv, wlv);
        for (int b = 0; b < 4; ++b) {
            const float* xb = x + b * PP;
            proj3<<<dim3(64, 3), 256, 0, stream>>>(
                xb, whq, wlq, bq, whk, wlk, bk, whv, wlv, bv, qh, kh, vv);
            kfrag_make<<<dim3(128, 1), 256, 0, stream>>>(kh, (uint4*)kfr);
            vfrag_make<<<dim3(32, 8, 1), 256, 0, stream>>>(vv, (uint4*)vfr);
            attn_flash11<<<dim3(128), 256, 0, stream>>>(
                qh, (const uint4*)kfr, (const uint4*)vfr, out + b * PP, 1);
        }
    }
}